// Round 9
// baseline (842.777 us; speedup 1.0000x reference)
//
#include <hip/hip_runtime.h>
#include <hip/hip_bf16.h>

// LSTM B=256,T=512,I=64,H=256. 64 WGs x 1024 thr, 4-way j-split.
// Weights register-resident (40 VGPR/thread). h exchange: u64 atomicExch
// publish (LLC-resident), poll via wide self-validating dwordx4 sc0+sc1
// loads (bypass L1+L2, read LLC) -- tagged words, no RMW poll serialization.

#define B_TOT 256
#define T_SEQ 512
#define NIN   64
#define HID   256
#define CHUNK 16
#define JSL   64            // j per WG (4-way split)
#define ROWB  768           // LDS act row stride bytes (320 f16 = 640B data)
#define NKK   10            // K = 320 = 10*32
#define NWG   64

typedef _Float16 half8 __attribute__((ext_vector_type(8)));
typedef float    f32x4 __attribute__((ext_vector_type(4)));
typedef unsigned u32x4 __attribute__((ext_vector_type(4)));

__device__ __forceinline__ float fast_rcp(float x){ return __builtin_amdgcn_rcpf(x); }
__device__ __forceinline__ float sigf(float v){ return fast_rcp(1.0f+__expf(-v)); }
__device__ __forceinline__ float tanhf_fast(float v){ return 1.0f-2.0f*fast_rcp(__expf(2.0f*v)+1.0f); }
__device__ __forceinline__ unsigned short f2h_bits(float f){
    _Float16 h=(_Float16)f; return __builtin_bit_cast(unsigned short,h);
}

__global__ void __launch_bounds__(1024, 4)
lstm_scan(const float* __restrict__ x,
          const float* __restrict__ Wih,
          const float* __restrict__ Whh,
          const float* __restrict__ bih,
          const float* __restrict__ bhh,
          const float* __restrict__ Wfc,
          const float* __restrict__ bfc,
          float* __restrict__ out,
          unsigned* __restrict__ hq)    // [2][B_TOT][HID] tagged h words
{
    __shared__ __align__(16) char act[CHUNK*ROWB];   // [16 rows][320 f16] swizzled
    __shared__ float gl[CHUNK][4*JSL + 1];           // [16][257] gate pre-acts

    const int tid  = threadIdx.x;
    const int w    = tid >> 6;       // wave 0..15 (= batch row in cell phase)
    const int lane = tid & 63;
    const int lr   = lane & 15;
    const int kg   = lane >> 4;
    const int chunk= blockIdx.x & 15;
    const int jw   = blockIdx.x >> 4;    // 0..3
    const int cb   = chunk*CHUNK;

    // this wave's 16 gate rows: n = gg*256 + jw*64 + (w&3)*16 + lr
    const int gg = w >> 2;
    const int n  = gg*HID + jw*JSL + (w & 3)*16 + lr;

    // ---- register-resident weight fragments (B operand), 40 VGPRs ----
    half8 wv[NKK];
    const float bias = bih[n] + bhh[n];
    #pragma unroll
    for (int kk = 0; kk < 2; ++kk)
        #pragma unroll
        for (int jj = 0; jj < 8; ++jj)
            wv[kk][jj] = (_Float16)Wih[n*NIN + kk*32 + kg*8 + jj];
    #pragma unroll
    for (int kk = 2; kk < NKK; ++kk)
        #pragma unroll
        for (int jj = 0; jj < 8; ++jj)
            wv[kk][jj] = (_Float16)Whh[n*HID + kk*32 + kg*8 + jj - NIN];

    // ---- init act: zeros (h_0 = 0) then x_0 ----
    for (int i = tid; i < CHUNK*ROWB/4; i += 1024) ((int*)act)[i] = 0;
    __syncthreads();
    {
        float x0 = x[((size_t)(cb + w)*T_SEQ + 0)*NIN + lane];
        *(unsigned short*)(act + w*ROWB + ((lane*2) ^ (w << 4))) = f2h_bits(x0);
    }
    __syncthreads();

    float cst = 0.f, hlast = 0.f;

    const int pj1 = (jw + 1) & 3, pj2 = (jw + 2) & 3, pj3 = (jw + 3) & 3;
    // gather role for this lane: partner p (0..2), 16B chunk q (0..15)
    const int gp   = lane >> 4;                 // 0..3 (3 = idle)
    const int gq   = lane & 15;
    const int gpj  = (jw + 1 + gp) & 3;         // partner j-slice for gp<3

    for (int t = 0; t < T_SEQ; ++t) {
        const int tn = (t+1 < T_SEQ) ? t+1 : T_SEQ-1;
        const float xv = x[((size_t)(cb + w)*T_SEQ + tn)*NIN + lane];

        // A fragments from act (row lr, swizzled, conflict-free)
        half8 af[NKK];
        #pragma unroll
        for (int kk = 0; kk < NKK; ++kk) {
            const int off = (kk*64 + kg*16) ^ (lr << 4);
            af[kk] = *(const half8*)(act + lr*ROWB + off);
        }
        f32x4 acc = {bias, bias, bias, bias};
        #pragma unroll
        for (int kk = 0; kk < NKK; ++kk)
            acc = __builtin_amdgcn_mfma_f32_16x16x32_f16(af[kk], wv[kk], acc, 0, 0, 0);

        // scatter pre-activations: (row kg*4+r, col w*16+lr)
        #pragma unroll
        for (int r = 0; r < 4; ++r)
            gl[kg*4 + r][w*16 + lr] = acc[r];
        __syncthreads();   // B1: gl ready; af reads done -> act writable

        // cell update: thread owns (row=w, jloc=lane)
        const float iv = sigf(gl[w][          lane]);
        const float fv = sigf(gl[w][  JSL  + lane]);
        const float gv = tanhf_fast(gl[w][2*JSL + lane]);
        const float ov = sigf(gl[w][3*JSL + lane]);
        const float cc = fv*cst + iv*gv;
        cst = cc;
        const float hv = ov*tanhf_fast(cc);
        hlast = hv;
        const unsigned short h16 = f2h_bits(hv);

        const unsigned tgt = (unsigned)(t+1);
        unsigned* hb = hq + ((size_t)(tgt & 1u)*B_TOT + (cb + w))*HID;

        // publish: pair lanes, 64-bit atomicExch (RMW executes AT the LLC,
        // line stays resident; half the op count of per-word exch)
        {
            const unsigned myword = (tgt << 16) | (unsigned)h16;
            const unsigned other  = __shfl_xor(myword, 1);
            if (!(lane & 1)) {
                const unsigned long long pk =
                    ((unsigned long long)other << 32) | (unsigned long long)myword;
                (void)__hip_atomic_exchange(
                    (unsigned long long*)(hb + jw*JSL + lane), pk,
                    __ATOMIC_RELAXED, __HIP_MEMORY_SCOPE_AGENT);
            }
        }

        // own h + x_{t+1} into act while the publish propagates
        {
            const int c = NIN + jw*JSL + lane;
            *(unsigned short*)(act + w*ROWB + ((c*2) ^ (w << 4))) = h16;
            if (t < T_SEQ-1)
                *(unsigned short*)(act + w*ROWB + ((lane*2) ^ (w << 4))) = f2h_bits(xv);
        }

        // gather: lanes 0-47 poll 3 partner row-slices with wide
        // self-validating loads (sc0+sc1: bypass L1 and L2, read the LLC)
        {
            u32x4 vv;
            const unsigned* ap = hb + (gpj*JSL + gq*4);
            for (;;) {
                unsigned f = 0u;
                if (gp < 3) {
                    asm volatile(
                        "global_load_dwordx4 %0, %1, off sc0 sc1\n\t"
                        "s_waitcnt vmcnt(0)"
                        : "=v"(vv) : "v"(ap) : "memory");
                    f = ((vv[0]>>16)^tgt)|((vv[1]>>16)^tgt)
                      | ((vv[2]>>16)^tgt)|((vv[3]>>16)^tgt);
                }
                if (!__any(f != 0u)) break;
            }
            if (gp < 3) {
                const int c0 = NIN + gpj*JSL + gq*4;
                const unsigned d0 = (vv[0] & 0xFFFFu) | (vv[1] << 16);
                const unsigned d1 = (vv[2] & 0xFFFFu) | (vv[3] << 16);
                *(unsigned long long*)(act + w*ROWB + ((c0*2) ^ (w << 4))) =
                    ((unsigned long long)d1 << 32) | (unsigned long long)d0;
            }
        }

        __syncthreads();   // B2: act ready for next step
    }

    // ---- final FC: partial dot over this WG's 64 j, atomicAdd into out ----
    {
        float v = Wfc[jw*JSL + lane] * hlast;
        if (jw == 0 && lane == 0) v += bfc[0];
        #pragma unroll
        for (int off = 32; off; off >>= 1) v += __shfl_down(v, off);
        if (lane == 0) atomicAdd(&out[cb + w], v);
    }
}

extern "C" void kernel_launch(void* const* d_in, const int* in_sizes, int n_in,
                              void* d_out, int out_size, void* d_ws, size_t ws_size,
                              hipStream_t stream)
{
    const float* x   = (const float*)d_in[0];
    const float* Wih = (const float*)d_in[1];
    const float* Whh = (const float*)d_in[2];
    const float* bih = (const float*)d_in[3];
    const float* bhh = (const float*)d_in[4];
    const float* Wfc = (const float*)d_in[5];
    const float* bfc = (const float*)d_in[6];
    float* out = (float*)d_out;

    unsigned* hq = (unsigned*)d_ws;   // [2][256][256] tagged words

    hipMemsetAsync(hq, 0, (size_t)2*B_TOT*HID*sizeof(unsigned), stream);
    hipMemsetAsync(d_out, 0, out_size*sizeof(float), stream);
    lstm_scan<<<NWG, 1024, 0, stream>>>(x, Wih, Whh, bih, bhh, Wfc, bfc,
                                        out, hq);
}